// Round 4
// baseline (1368.584 us; speedup 1.0000x reference)
//
#include <hip/hip_runtime.h>

// ---------------------------------------------------------------------------
// ATKT forward, all-f16 MFMA pipeline.
//   prep  -> casts + bias/qvec precompute
//   embed -> sa_emb (f32 out) + fused gather row index ridx
//   tgemm -> T tables: T1=se@Wl^T+q0, T0=se@Wr^T+q1, permuted f16 store
//   lstm  -> R7: 32 WGs x 2 batch rows (R6 structure) with LDS diet:
//            (a) compact h[2][2][256] + broadcast-zero A reads (A rows 2..15
//                are zero; 56/64 lanes read ONE shared 16B zero block),
//            (b) conflict-free redistribution layout [par][r2][l16],
//            (c) half4 T-gather (lane loads exactly its 4 gate values).
//            LDS pipe ~2600 -> ~1800 cyc/step < matrix 2480 -> MFMA-bound.
//   mlp gemm -> att -> scan (softmax-as-prefix-scan) -> fc gemm (sigmoid)
// R6 post-mortem: step 4240 cyc = MFMA 2480 + LDS co-bottleneck 2600 (hA
// full-width zero reads 768 + ldsB 1536 + conflicted redist). R7 removes the
// removable LDS terms; ldsB 16 frags/wave stay (reg budget exhausted at 48).
// ---------------------------------------------------------------------------

typedef _Float16 half8 __attribute__((ext_vector_type(8)));
typedef _Float16 half4 __attribute__((ext_vector_type(4)));
typedef float f32x4 __attribute__((ext_vector_type(4)));

#define BS 32768
#define NC 1000

__device__ __forceinline__ float sigm(float x) {
    return __builtin_amdgcn_rcpf(1.f + __expf(-x));
}
__device__ __forceinline__ float tanh_(float x) {
    float e = __expf(2.f * x);
    return 1.f - 2.f * __builtin_amdgcn_rcpf(e + 1.f);
}

// ---------------------------------------------------------------------------
// prep: f32->f16 casts, bsum=bih+bhh, qvec[0]=ae[1]@Wr^T+bsum, qvec[1]=ae[0]@Wl^T+bsum
// ---------------------------------------------------------------------------
__global__ void prep_kernel(const float* __restrict__ Wih, const float* __restrict__ fcW,
                            const float* __restrict__ mlpW, const float* __restrict__ se,
                            const float* __restrict__ ae, const float* __restrict__ bih,
                            const float* __restrict__ bhh,
                            _Float16* __restrict__ wih16, _Float16* __restrict__ fcw16,
                            _Float16* __restrict__ mlpw16, _Float16* __restrict__ se16,
                            float* __restrict__ bsum, float* __restrict__ qvec) {
    int i = blockIdx.x * 256 + threadIdx.x;
    if (i < 524288) {
        wih16[i] = (_Float16)Wih[i];
    } else if (i < 1048576) {
        int j = i - 524288;                 // fcw padded 1024x512
        int r = j >> 9;
        fcw16[j] = (r < NC) ? (_Float16)fcW[j] : (_Float16)0.f;
    } else if (i < 1081344) {
        int j = i - 1048576;                // mlpw padded 128x256
        int r = j >> 8;
        mlpw16[j] = (r < 80) ? (_Float16)mlpW[j] : (_Float16)0.f;
    } else if (i < 1337600) {
        int j = i - 1081344;                // se 1001x256
        se16[j] = (_Float16)se[j];
    } else if (i < 1338624) {
        int j = i - 1337600;
        bsum[j] = bih[j] + bhh[j];
    } else if (i < 1340672) {
        int j = i - 1338624;                // qvec 2x1024
        int which = j >> 10, col = j & 1023;
        int aerow = (which == 0) ? 1 : 0;   // T1 uses ae[1]@Wr; T0 uses ae[0]@Wl
        int koff  = (which == 0) ? 256 : 0;
        float s = 0.f;
        for (int k = 0; k < 256; k++)
            s += ae[aerow * 256 + k] * Wih[(size_t)col * 512 + koff + k];
        qvec[j] = s + bih[col] + bhh[col];
    }
}

// ---------------------------------------------------------------------------
// embed: sa_emb f32 output + ridx (row into T table: ans==1 ? sk : 1024+sk)
// ---------------------------------------------------------------------------
__global__ void embed_kernel(const int* __restrict__ skill, const int* __restrict__ answer,
                             const float* __restrict__ se, const float* __restrict__ ae,
                             float* __restrict__ sa_out, int* __restrict__ ridx) {
    int token = blockIdx.x;
    int sk = skill[token], an = answer[token];
    const float* first  = (an == 1) ? (se + (size_t)sk * 256) : (ae + (size_t)an * 256);
    const float* second = (an == 1) ? (ae + (size_t)an * 256) : (se + (size_t)sk * 256);
    int j = threadIdx.x * 4;
    const float* src = (j < 256) ? (first + j) : (second + (j - 256));
    float4 v = *(const float4*)src;
    *(float4*)(sa_out + (size_t)token * 512 + j) = v;
    if (threadIdx.x == 0) ridx[token] = (an == 1) ? sk : (1024 + sk);
}

// ---------------------------------------------------------------------------
// tgemm: T tables (2048x1024), A=se16 (row-clamped), B=wih16 (ldB=512,+koff),
// epilogue adds qvec and stores f16 permuted for half4 lstm gathers:
//   col = g*256 + wv*32 + pr*16 + hcLow  ->
//   perm = ((col&255)>>5)*128 + ((col>>4)&1)*64 + (col&15)*4 + (col>>8)
// (lane (wv, pr, hcLow) loads half4 = gates 0..3 at wv*128+pr*64+hcLow*4.)
// ---------------------------------------------------------------------------
__global__ __launch_bounds__(256) void tgemm_kernel(
        const _Float16* __restrict__ A, const _Float16* __restrict__ Bw,
        const float* __restrict__ qvec, _Float16* __restrict__ Tsw) {
    int bm = blockIdx.x * 128, bn = blockIdx.y * 128;
    int which = bm >> 10;
    int mbase = bm & 1023;
    int koff = which ? 256 : 0;
    int tid = threadIdx.x, wv = tid >> 6, lane = tid & 63;
    int quad = lane >> 4, l16 = lane & 15;
    int wm = (wv & 1) * 64, wn = (wv >> 1) * 64;

    int arow[4];
#pragma unroll
    for (int i = 0; i < 4; i++) {
        int r = mbase + wm + i * 16 + l16;
        arow[i] = (r > 1000) ? 1000 : r;
    }
    const _Float16* Bbase = Bw + (size_t)(bn + wn + l16) * 512 + koff + quad * 8;

    f32x4 acc[4][4] = {};
    for (int kk = 0; kk < 256; kk += 32) {
        half8 a[4], b[4];
#pragma unroll
        for (int i = 0; i < 4; i++)
            a[i] = *(const half8*)(A + (size_t)arow[i] * 256 + quad * 8 + kk);
#pragma unroll
        for (int j = 0; j < 4; j++)
            b[j] = *(const half8*)(Bbase + (size_t)j * 16 * 512 + kk);
#pragma unroll
        for (int i = 0; i < 4; i++)
#pragma unroll
            for (int j = 0; j < 4; j++)
                acc[i][j] = __builtin_amdgcn_mfma_f32_16x16x32_f16(a[i], b[j], acc[i][j], 0, 0, 0);
    }
#pragma unroll
    for (int j = 0; j < 4; j++) {
        int col = bn + wn + j * 16 + l16;
        float qv = qvec[which * 1024 + col];
        int perm = ((col & 255) >> 5) * 128 + (((col >> 4) & 1)) * 64 + (col & 15) * 4 + (col >> 8);
#pragma unroll
        for (int i = 0; i < 4; i++) {
            int row = mbase + wm + i * 16 + quad * 4;
#pragma unroll
            for (int r = 0; r < 4; r++) {
                if (row + r > 1000) continue;
                Tsw[(size_t)((which << 10) + row + r) * 1024 + perm] = (_Float16)(acc[i][j][r] + qv);
            }
        }
    }
}

// ---------------------------------------------------------------------------
// LSTM, R7. 32 WGs x 512 threads (8 waves, 2/SIMD). WG owns batch rows
// {2*bid, 2*bid+1}. Wave w owns hidden cols [32w,32w+32).
// LDS map (bytes from smem):
//   [0      .. 131072) ldsB : 8 waves * 16 frags * 512 f16 (Whh k=6,7)
//   [131072 .. 133120) hC   : [2 buf][2 row][256] f16 compact h
//   [133120 .. 133136) zero : 16B shared zero block (A rows 2..15)
//   [133152 .. 141344) rd   : 8 waves * 256 f32 redistribution
// A-read: real lanes (l16<2) read 16B of hC; other 56 lanes broadcast-read
// the zero block (same-address -> conflict-free). Redist layout [par][r2][l16]
// -> 16B-stride stores, 2-way free. T gather = half4 (8B/lane).
// ---------------------------------------------------------------------------
__global__ __launch_bounds__(512, 2) void lstm_kernel(
        const float* __restrict__ Whh,          // [1024][256] f32
        const _Float16* __restrict__ Tsw,       // [2048][1024] f16 permuted
        const int* __restrict__ ridxArr,        // [B*S]
        _Float16* __restrict__ outH) {          // [b*512+t][256] f16
    int bid = blockIdx.x;                       // 0..31
    int tid = threadIdx.x, wv = tid >> 6, lane = tid & 63;
    int quad = lane >> 4, l16 = lane & 15;
    int row = lane >> 5;                        // 0..1: batch row this lane updates
    int hc  = lane & 31;                        // hidden col within wave's 32
    int pr = hc >> 4, hcLow = hc & 15;

    extern __shared__ char smem[];
    _Float16* ldsB = (_Float16*)smem;                  // 131072 B
    float*    rd   = (float*)(smem + 133152);          // 8192 B

    // ---- fill Whh fragments (f32 -> f16): k<6 -> VGPR, k>=6 -> LDS ----
    half8 rB[48];
#pragma unroll
    for (int v = 0; v < 8; v++) {
#pragma unroll
        for (int k = 0; k < 8; k++) {
            int col = (v >> 1) * 256 + wv * 32 + (v & 1) * 16 + l16;
            const float* p = Whh + (size_t)col * 256 + k * 32 + quad * 8;
            float4 x0 = *(const float4*)p;
            float4 x1 = *(const float4*)(p + 4);
            half8 hb;
            hb[0] = (_Float16)x0.x; hb[1] = (_Float16)x0.y; hb[2] = (_Float16)x0.z; hb[3] = (_Float16)x0.w;
            hb[4] = (_Float16)x1.x; hb[5] = (_Float16)x1.y; hb[6] = (_Float16)x1.z; hb[7] = (_Float16)x1.w;
            if (k < 6) rB[k * 8 + v] = hb;
            else *(half8*)(ldsB + ((size_t)wv * 16 + (k - 6) * 8 + v) * 512 + lane * 8) = hb;
        }
    }
    // zero hC (both buffers) + the shared zero block: 130 * 16B = 2080 B
    if (tid < 130) ((float4*)(smem + 131072))[tid] = float4{0.f, 0.f, 0.f, 0.f};

    int b0 = bid * 2 + row;
    int tb = b0 * 512;
    _Float16* po = outH + (size_t)b0 * 512 * 256 + wv * 32 + hc;

    // per-lane A-read bases (byte offsets into smem), k-step advance
    bool realA = (l16 < 2);
    int hb0 = realA ? (131072 + l16 * 512 + quad * 16) : 133120;
    int hb1 = realA ? (131072 + 1024 + l16 * 512 + quad * 16) : 133120;
    int kstep = realA ? 64 : 0;

    float c = 0.f;
    // prologue gathers (half4 T + next ridx per lane)
    half4 Tcur;
    unsigned ridxA;
    {
        int r0 = ridxArr[tb];
        Tcur = *(const half4*)(Tsw + (size_t)r0 * 1024 + wv * 128 + pr * 64 + hcLow * 4);
        ridxA = ridxArr[tb + 1];
    }
    __syncthreads();

    int cur = 0;
    for (int t = 0; t < 512; t++) {
        // prefetch next T row + index two ahead
        int tn2 = (t + 2 < 512) ? t + 2 : 511;
        half4 Tnx = *(const half4*)(Tsw + (size_t)ridxA * 1024 + wv * 128 + pr * 64 + hcLow * 4);
        unsigned ridxB = ridxArr[tb + tn2];

        f32x4 acc[8];
#pragma unroll
        for (int v = 0; v < 8; v++) acc[v] = f32x4{0.f, 0.f, 0.f, 0.f};

        const char* hp = smem + (cur ? hb1 : hb0);
#pragma unroll
        for (int k = 0; k < 8; k++) {
            half8 av = *(const half8*)hp;
            hp += kstep;
#pragma unroll
            for (int v = 0; v < 8; v++) {
                half8 bv;
                if (k < 6) bv = rB[k * 8 + v];
                else bv = *(const half8*)(ldsB + ((size_t)wv * 16 + (k - 6) * 8 + v) * 512 + lane * 8);
                acc[v] = __builtin_amdgcn_mfma_f32_16x16x32_f16(av, bv, acc[v], 0, 0, 0);
            }
        }

        // ---- in-wave redistribution: quad0's 2 real rows -> all 64 lanes ----
        // rd layout (f32x4 slots per wave): slot = par*32 + r2*16 + l16
        if (quad == 0) {
#pragma unroll
            for (int r2 = 0; r2 < 2; r2++)
#pragma unroll
                for (int par = 0; par < 2; par++) {
                    f32x4 pv;
                    pv[0] = acc[0 + par][r2];
                    pv[1] = acc[2 + par][r2];
                    pv[2] = acc[4 + par][r2];
                    pv[3] = acc[6 + par][r2];
                    *(f32x4*)(rd + wv * 256 + (par * 32 + r2 * 16 + l16) * 4) = pv;
                }
        }
        f32x4 pa = *(const f32x4*)(rd + wv * 256 + (pr * 32 + row * 16 + hcLow) * 4);

        float ii = sigm(pa[0] + (float)Tcur[0]);
        float ff = sigm(pa[1] + (float)Tcur[1]);
        float gg = tanh_(pa[2] + (float)Tcur[2]);
        float oo = sigm(pa[3] + (float)Tcur[3]);
        c = ff * c + ii * gg;
        float h = oo * tanh_(c);
        _Float16 hf = (_Float16)h;

        // write new h into the OTHER compact buffer: [buf][row][col=wv*32+hc]
        *(_Float16*)(smem + 131072 + ((cur ^ 1) << 10) + (row << 9) + (wv * 32 + hc) * 2) = hf;

        __syncthreads();   // hC[cur^1] complete for step t+1
        cur ^= 1;

        // post-barrier: outH store drains during next step's compute
        po[0] = hf;
        po += 256;
        Tcur = Tnx;
        ridxA = ridxB;
    }
}

// ---------------------------------------------------------------------------
// Generic f16 MFMA GEMM: C = A @ Bw^T (+bias), epi 1 = sigmoid. Direct-global.
// ---------------------------------------------------------------------------
__global__ __launch_bounds__(256) void gemm_f16(
        const _Float16* __restrict__ A, const _Float16* __restrict__ Bw,
        const float* __restrict__ bias, float* __restrict__ C,
        int K, int ldC, int Nstore, int epi) {
    int bm = blockIdx.x * 128, bn = blockIdx.y * 128;
    int tid = threadIdx.x, wv = tid >> 6, lane = tid & 63;
    int quad = lane >> 4, l16 = lane & 15;
    int wm = (wv & 1) * 64, wn = (wv >> 1) * 64;

    const _Float16* Abase = A + (size_t)(bm + wm + l16) * K + quad * 8;
    const _Float16* Bbase = Bw + (size_t)(bn + wn + l16) * K + quad * 8;

    f32x4 acc[4][4] = {};
    for (int kk = 0; kk < K; kk += 32) {
        half8 a[4], b[4];
#pragma unroll
        for (int i = 0; i < 4; i++) a[i] = *(const half8*)(Abase + (size_t)i * 16 * K + kk);
#pragma unroll
        for (int j = 0; j < 4; j++) b[j] = *(const half8*)(Bbase + (size_t)j * 16 * K + kk);
#pragma unroll
        for (int i = 0; i < 4; i++)
#pragma unroll
            for (int j = 0; j < 4; j++)
                acc[i][j] = __builtin_amdgcn_mfma_f32_16x16x32_f16(a[i], b[j], acc[i][j], 0, 0, 0);
    }
#pragma unroll
    for (int j = 0; j < 4; j++) {
        int col = bn + wn + j * 16 + l16;
        if (col >= Nstore) continue;
        float bv = bias ? bias[col] : 0.f;
#pragma unroll
        for (int i = 0; i < 4; i++) {
            int row0 = bm + wm + i * 16 + quad * 4;
#pragma unroll
            for (int r = 0; r < 4; r++) {
                float v = acc[i][j][r] + bv;
                if (epi == 1) v = sigm(v);
                C[(size_t)(row0 + r) * ldC + col] = v;
            }
        }
    }
}

// ---------------------------------------------------------------------------
__global__ void att_kernel(const float* __restrict__ mlpout, const float* __restrict__ simW,
                           float* __restrict__ att) {
    int m = blockIdx.x * 256 + threadIdx.x;
    float s = 0.f;
#pragma unroll
    for (int d = 0; d < 80; d += 4) {
        float4 v = *(const float4*)(mlpout + (size_t)m * 80 + d);
        float4 w = *(const float4*)(simW + d);
        s += tanh_(v.x) * w.x + tanh_(v.y) * w.y + tanh_(v.z) * w.z + tanh_(v.w) * w.w;
    }
    att[m] = s;
}

// ---------------------------------------------------------------------------
// Attention as prefix scan; writes final = [attn_cum_1 | out] f16.
// ---------------------------------------------------------------------------
__global__ __launch_bounds__(256) void scan_kernel(const float* __restrict__ att,
                                                   const _Float16* __restrict__ outH,
                                                   _Float16* __restrict__ finalB) {
    int b = blockIdx.x, d = threadIdx.x;
    __shared__ float w_s[512];
    for (int i = d; i < 512; i += 256) w_s[i] = __expf(att[(size_t)b * 512 + i]);
    __syncthreads();

    float S = 0.f, W = 0.f, C = 0.f;
    const _Float16* op = outH + (size_t)b * 512 * 256 + d;
    _Float16* fp = finalB + (size_t)b * 512 * 512 + d;
    for (int i = 0; i < 512; i++) {
        float w = w_s[i];
        float ov = (float)op[(size_t)i * 256];
        S += w * ov;
        W += w;
        float ao = S * __builtin_amdgcn_rcpf(W);
        fp[(size_t)i * 512]       = (_Float16)C;
        fp[(size_t)i * 512 + 256] = (_Float16)ov;
        C += ao;
    }
}

// ---------------------------------------------------------------------------
extern "C" void kernel_launch(void* const* d_in, const int* in_sizes, int n_in,
                              void* d_out, int out_size, void* d_ws, size_t ws_size,
                              hipStream_t stream) {
    const int*   skill      = (const int*)d_in[0];
    const int*   answer     = (const int*)d_in[1];
    const float* skill_emb  = (const float*)d_in[2];
    const float* answer_emb = (const float*)d_in[3];
    const float* Wih        = (const float*)d_in[4];
    const float* Whh        = (const float*)d_in[5];
    const float* bih        = (const float*)d_in[6];
    const float* bhh        = (const float*)d_in[7];
    const float* mlp_W      = (const float*)d_in[8];
    const float* mlp_b      = (const float*)d_in[9];
    const float* sim_W      = (const float*)d_in[10];
    const float* fc_W       = (const float*)d_in[11];
    const float* fc_b       = (const float*)d_in[12];

    float* res    = (float*)d_out;               // [32768][1000]
    float* sa_out = res + (size_t)BS * NC;       // [32768][512]

    char* ws = (char*)d_ws;
    _Float16* outH   = (_Float16*)(ws);                 // 16,777,216 B
    _Float16* finalB = (_Float16*)(ws + 16777216);      // 33,554,432
    _Float16* wih16  = (_Float16*)(ws + 50331648);      //  1,048,576
    _Float16* fcw16  = (_Float16*)(ws + 51380224);      //  1,048,576
    _Float16* mlpw16 = (_Float16*)(ws + 52428800);      //     65,536
    _Float16* se16   = (_Float16*)(ws + 52494336);      //    524,288 (512,512 used)
    float*    bsum   = (float*)(ws + 53018624);         //      4,096
    float*    qvec   = (float*)(ws + 53022720);         //      8,192
    float*    att    = (float*)(ws + 53030912);         //    131,072
    float*    mlpout = (float*)(ws + 53161984);         // 10,485,760
    _Float16* Tsw    = (_Float16*)(ws + 63647744);      //  4,194,304
    int*      ridx   = (int*)(ws + 67842048);           //    131,072

    (void)bsum; (void)in_sizes; (void)n_in; (void)out_size; (void)ws_size;

    hipLaunchKernelGGL(prep_kernel, dim3(5238), dim3(256), 0, stream,
                       Wih, fc_W, mlp_W, skill_emb, answer_emb, bih, bhh,
                       wih16, fcw16, mlpw16, se16, bsum, qvec);
    hipLaunchKernelGGL(embed_kernel, dim3(BS), dim3(128), 0, stream,
                       skill, answer, skill_emb, answer_emb, sa_out, ridx);
    hipLaunchKernelGGL(tgemm_kernel, dim3(16, 8), dim3(256), 0, stream,
                       se16, wih16, qvec, Tsw);

    hipFuncSetAttribute((const void*)lstm_kernel,
                        hipFuncAttributeMaxDynamicSharedMemorySize, 141344);
    hipLaunchKernelGGL(lstm_kernel, dim3(32), dim3(512), 141344, stream,
                       Whh, Tsw, ridx, outH);

    hipLaunchKernelGGL(gemm_f16, dim3(256, 1), dim3(256), 0, stream,
                       outH, mlpw16, mlp_b, mlpout, 256, 80, 80, 0);
    hipLaunchKernelGGL(att_kernel, dim3(128), dim3(256), 0, stream, mlpout, sim_W, att);
    hipLaunchKernelGGL(scan_kernel, dim3(64), dim3(256), 0, stream, att, outH, finalB);
    hipLaunchKernelGGL(gemm_f16, dim3(256, 8), dim3(256), 0, stream,
                       finalB, fcw16, fc_b, res, 512, 1000, 1000, 1);
}